// Round 9
// baseline (261.666 us; speedup 1.0000x reference)
//
#include <hip/hip_runtime.h>

#define Bb 2
#define Nn 256
#define Dd 128
#define Rr 32

typedef unsigned short u16;
typedef unsigned int   u32;
typedef __attribute__((ext_vector_type(8))) short bf16x8;
typedef __attribute__((ext_vector_type(4))) float f32x4;
typedef __attribute__((ext_vector_type(2))) u32   u32x2;

__device__ __forceinline__ short f2bfs(float f){
  u32 u = __float_as_uint(f);
  u += 0x7FFFu + ((u >> 16) & 1u);   // RNE
  return (short)(u >> 16);
}
__device__ __forceinline__ u16 f2bf(float f){
  u32 u = __float_as_uint(f);
  u += 0x7FFFu + ((u >> 16) & 1u);
  return (u16)(u >> 16);
}

// ---- kernel 1: h_T[b][d][i] = (node_s @ src_w)^T  (fp32) -------------------
__global__ __launch_bounds__(128) void hproj_kernel(
    const float* __restrict__ node_s, const float* __restrict__ src_w,
    float* __restrict__ hT_out){
  __shared__ float s_row[Dd];
  const int bi = blockIdx.x, d = threadIdx.x;
  const int b = bi >> 8, i = bi & 255;
  s_row[d] = node_s[(size_t)bi*Dd + d];
  __syncthreads();
  float acc = 0.f;
  #pragma unroll 8
  for (int k=0;k<Dd;k++) acc += s_row[k]*src_w[k*Dd + d];
  hT_out[((size_t)b*Dd + d)*Nn + i] = acc;   // transposed: [d][j]
}

// ---- kernel 2: all-MFMA pipeline, one block per (b,i), 8 waves -------------
// Waves 0-3: j half [0,128); waves 4-7: j half [128,256).
// Within a half, wave ws owns d-cols [ws*32, ws*32+32).
// rbf fragments register-cached across the p loop (loaded once).
__global__ __launch_bounds__(512,4) void se3_mfma6(
    const float* __restrict__ node_v,
    const float* __restrict__ rbf,
    const float* __restrict__ r_hat,
    const float* __restrict__ maskp,
    const float* __restrict__ r0w1, const float* __restrict__ r0b1,
    const float* __restrict__ r0w2, const float* __restrict__ r0b2,
    const float* __restrict__ r1w1, const float* __restrict__ r1b1,
    const float* __restrict__ r1w2, const float* __restrict__ r1b2,
    const float* __restrict__ r2w1, const float* __restrict__ r2b1,
    const float* __restrict__ r2w2, const float* __restrict__ r2b2,
    const float* __restrict__ r3w1, const float* __restrict__ r3b1,
    const float* __restrict__ r3w2, const float* __restrict__ r3b2,
    const float* __restrict__ ln_g, const float* __restrict__ ln_b,
    const float* __restrict__ out_w, const float* __restrict__ out_b,
    const float* __restrict__ v_scale, const float* __restrict__ t_scale,
    const float* __restrict__ hT,
    float* __restrict__ out_s, float* __restrict__ out_v, float* __restrict__ out_t)
{
  // LDS total = 69,336 B (2 blocks/CU)
  __shared__ u16   s_hid[2][64*136];   // 34816: hidden per half, [j][hid]
  __shared__ u16   s_G[8*32*40];       // 20480: per-wave G_T[d][j(32)]
  __shared__ u16   s_YT[10*264];       //  5280: 0=mask,1-3=Y1*m,4-8=Y2*m,9=mask
  __shared__ u16   s_Y1r[3*264];       //  1584: raw Y1 (dot MFMA A)
  __shared__ float s_redh[Dd][10];     //  5120: cross-half partials
  __shared__ float s_msg[Dd];          //   512
  __shared__ float s_xn[Dd];           //   512
  __shared__ float s_part[4][Dd];      //  2048
  __shared__ float s_mv[2];            //     8

  const int tid  = threadIdx.x;
  const int bi   = blockIdx.x;            // b*N + i
  const int b    = bi >> 8;
  const int lane = tid & 63;
  const int w    = tid >> 6;              // wave 0..7
  const int half = w >> 2;                // j half
  const int ws   = w & 3;                 // wave-in-set
  const int q    = lane >> 4;             // quad
  const int cc   = lane & 15;
  const int dbase= ws*32;
  const int jbH  = half*128;              // this half's j base

  // ---- setup: stacked-Y rows (mask folded), raw Y1 (one j per thread) ----
  if (tid < Nn){
    int j = tid;
    size_t pidx = (size_t)bi*Nn + j;
    float mk = maskp[pidx];
    float x = r_hat[pidx*3+0];
    float y = r_hat[pidx*3+1];
    float z = r_hat[pidx*3+2];
    const float SQ3=1.7320508075688772f;   // sqrt(3)
    const float C15=3.8729833462074170f;   // sqrt(15)
    const float C5H=1.1180339887498949f;   // 0.5*sqrt(5)
    float y1a=SQ3*x, y1b=SQ3*y, y1c=SQ3*z;
    s_YT[0*264+j]=f2bf(mk);
    s_YT[1*264+j]=f2bf(y1a*mk);
    s_YT[2*264+j]=f2bf(y1b*mk);
    s_YT[3*264+j]=f2bf(y1c*mk);
    s_YT[4*264+j]=f2bf(C15*x*y*mk);
    s_YT[5*264+j]=f2bf(C15*y*z*mk);
    s_YT[6*264+j]=f2bf(C5H*(3.f*z*z-1.f)*mk);
    s_YT[7*264+j]=f2bf(C15*x*z*mk);
    s_YT[8*264+j]=f2bf(0.5f*C15*(x*x-y*y)*mk);
    s_YT[9*264+j]=f2bf(mk);
    s_Y1r[0*264+j]=f2bf(y1a);
    s_Y1r[1*264+j]=f2bf(y1b);
    s_Y1r[2*264+j]=f2bf(y1c);
  }

  const float* rbf_blk = rbf + (size_t)bi*Nn*Rr;

  // ---- rbf fragments for this half, cached in registers (32 VGPR) ----
  bf16x8 rf[8];
  #pragma unroll
  for (int t=0;t<8;t++){
    const float* rp = rbf_blk + (size_t)(jbH + t*16 + cc)*Rr + q*8;
    f32x4 a0 = *(const f32x4*)rp;
    f32x4 a1 = *(const f32x4*)(rp+4);
    rf[t] = (bf16x8){f2bfs(a0[0]),f2bfs(a0[1]),f2bfs(a0[2]),f2bfs(a0[3]),
                     f2bfs(a1[0]),f2bfs(a1[1]),f2bfs(a1[2]),f2bfs(a1[3])};
  }

  // ---- node_v B-fragments for the dot MFMA: B[k=c][n=d], k<3 on quad 0 ----
  bf16x8 vBf[2];
  {
    const float* nv = node_v + (size_t)bi*3*Dd;
    #pragma unroll
    for (int nt=0;nt<2;nt++){
      int dd = dbase+nt*16+cc;
      bf16x8 t = {0,0,0,0,0,0,0,0};
      if (q==0){
        t[0]=f2bfs(nv[0*Dd+dd]);
        t[1]=f2bfs(nv[1*Dd+dd]);
        t[2]=f2bfs(nv[2*Dd+dd]);
      }
      vBf[nt]=t;
    }
  }

  const f32x4 zf = {0.f,0.f,0.f,0.f};
  f32x4 accred[2] = {zf, zf};           // rows 0..9 = the 10 reduced outputs

  #pragma unroll 1
  for (int p=0;p<4;p++){
    const float* W1p = (p==0)?r0w1:(p==1)?r1w1:(p==2)?r2w1:r3w1;
    const float* B1p = (p==0)?r0b1:(p==1)?r1b1:(p==2)?r2b1:r3b1;
    const float* W2p = (p==0)?r0w2:(p==1)?r1w2:(p==2)?r2w2:r3w2;
    const float* B2p = (p==0)?r0b2:(p==1)?r1b2:(p==2)?r2b2:r3b2;
    const int lo = (p==0)?0:(p==1)?1:(p==2)?4:9;
    const int hi = (p==0)?0:(p==1)?3:(p==2)?8:9;
    const u32 gmask = (cc>=lo && cc<=hi) ? 0xFFFFFFFFu : 0u;
    const u16* ytrow = &s_YT[(cc<10?cc:9)*264];

    // per-p fragments: w1f (A of GEMM1) 8 VGPR, w2f (B of GEMM2) 32 VGPR
    bf16x8 w1f[2];
    bf16x8 w2f[2][4];
    f32x4  b1q[2];                     // bias1[hid = dbase+mt*16+q*4+r]
    float  b2v[2];
    #pragma unroll
    for (int mt=0;mt<2;mt++){
      int dd = dbase+mt*16+cc;
      b1q[mt] = *(const f32x4*)(B1p + dbase + mt*16 + q*4);
      b2v[mt] = B2p[dd];
      #pragma unroll
      for (int jj=0;jj<8;jj++)
        w1f[mt][jj] = f2bfs(W1p[(q*8+jj)*Dd + dd]);
      #pragma unroll
      for (int ks=0;ks<4;ks++){
        #pragma unroll
        for (int jj=0;jj<8;jj++)
          w2f[mt][ks][jj] = f2bfs(W2p[(ks*32+q*8+jj)*Dd + dd]);
      }
    }

    #pragma unroll 1
    for (int ch=0; ch<2; ch++){          // 2 chunks of 64 j (this half)
      __syncthreads();                   // s_hid free (all waves' GEMM2 done)
      // ---- GEMM1 (swapped): C1[hid, j] = w1^T @ rbf^T; SiLU; b64 store ----
      #pragma unroll
      for (int jt=0;jt<4;jt++){
        bf16x8 raf = rf[ch*4+jt];
        #pragma unroll
        for (int mt=0;mt<2;mt++){
          f32x4 hc = __builtin_amdgcn_mfma_f32_16x16x32_bf16(w1f[mt], raf, zf, 0,0,0);
          u16 g4[4];
          #pragma unroll
          for (int r=0;r<4;r++){
            float x  = hc[r] + b1q[mt][r];
            float e  = __expf(-x);
            g4[r] = f2bf(x*__builtin_amdgcn_rcpf(1.f+e));
          }
          u32x2 pk = { (u32)g4[0] | ((u32)g4[1]<<16),
                       (u32)g4[2] | ((u32)g4[3]<<16) };
          *(u32x2*)&s_hid[half][(jt*16+cc)*136 + dbase + mt*16 + q*4] = pk;
        }
      }
      __syncthreads();                   // hidden ready
      // ---- GEMM2 + G + per-32j reduction MFMA ----
      #pragma unroll
      for (int pr=0;pr<2;pr++){          // pairs of m-tiles (32 j each)
        #pragma unroll
        for (int ml=0;ml<2;ml++){
          int m = pr*2+ml;
          bf16x8 af[4];
          #pragma unroll
          for (int ks=0;ks<4;ks++)
            af[ks] = *(const bf16x8*)&s_hid[half][(m*16+cc)*136 + ks*32 + q*8];

          f32x4 dotC[2];
          if (p==3){                     // dot(v, Y1) via K=3 MFMA
            bf16x8 aY = {0,0,0,0,0,0,0,0};
            if (q==0){
              int j = jbH + ch*64 + m*16 + cc;
              aY[0]=(short)s_Y1r[0*264+j];
              aY[1]=(short)s_Y1r[1*264+j];
              aY[2]=(short)s_Y1r[2*264+j];
            }
            #pragma unroll
            for (int nt=0;nt<2;nt++)
              dotC[nt] = __builtin_amdgcn_mfma_f32_16x16x32_bf16(aY, vBf[nt], zf, 0,0,0);
          }

          #pragma unroll
          for (int nt=0;nt<2;nt++){
            f32x4 c2 = zf;
            #pragma unroll
            for (int ks=0;ks<4;ks++)
              c2 = __builtin_amdgcn_mfma_f32_16x16x32_bf16(af[ks], w2f[nt][ks], c2, 0,0,0);
            int dd = dbase+nt*16+cc;
            u16 g4[4];
            if (p<3){
              f32x4 h4 = *(const f32x4*)(hT + ((size_t)(b*Dd) + dd)*Nn + jbH + ch*64 + m*16 + q*4);
              #pragma unroll
              for (int r=0;r<4;r++)
                g4[r] = f2bf((c2[r]+b2v[nt]) * h4[r]);
            } else {
              #pragma unroll
              for (int r=0;r<4;r++)
                g4[r] = f2bf((c2[r]+b2v[nt]) * dotC[nt][r]);
            }
            u32x2 pk = { (u32)g4[0] | ((u32)g4[1]<<16),
                         (u32)g4[2] | ((u32)g4[3]<<16) };
            *(u32x2*)&s_G[(w*32 + nt*16 + cc)*40 + ml*16 + q*4] = pk;
          }
        }
        // reduction over this pair's 32 j (intra-wave LDS: in-order, no barrier)
        {
          bf16x8 aR = *(const bf16x8*)(ytrow + jbH + ch*64 + pr*32 + q*8);
          u32* arp = (u32*)&aR;
          arp[0]&=gmask; arp[1]&=gmask; arp[2]&=gmask; arp[3]&=gmask;
          #pragma unroll
          for (int nt=0;nt<2;nt++){
            bf16x8 bG = *(const bf16x8*)&s_G[(w*32 + nt*16 + cc)*40 + q*8];
            accred[nt] = __builtin_amdgcn_mfma_f32_16x16x32_bf16(aR, bG, accred[nt], 0,0,0);
          }
        }
      }
    }
  }

  // ---- cross-half combine + scatter (rows 0..9 only!) ----
  if (half==1){
    #pragma unroll
    for (int nt=0;nt<2;nt++){
      int d = dbase + nt*16 + cc;
      #pragma unroll
      for (int r=0;r<4;r++){
        int rw = q*4 + r;
        if (rw < 10) s_redh[d][rw] = accred[nt][r];   // guard: rows 10..15 are zero/garbage
      }
    }
  }
  __syncthreads();
  if (half==0){
    #pragma unroll
    for (int nt=0;nt<2;nt++){
      int d = dbase + nt*16 + cc;
      #pragma unroll
      for (int r=0;r<4;r++){
        int rw = q*4 + r;
        float val = accred[nt][r] + ((rw<10) ? s_redh[d][rw] : 0.f);
        if (rw==0)      s_msg[d] = val;
        else if (rw<=3) out_v[(size_t)bi*3*Dd + (size_t)(rw-1)*Dd + d] = val*v_scale[d];
        else if (rw<=8) out_t[(size_t)bi*5*Dd + (size_t)(rw-4)*Dd + d] = val*t_scale[d];
        else if (rw==9) s_xn[d] = val;                // guard: rw 10..15 write nothing
      }
    }
  }
  __syncthreads();

  // ---- LayerNorm stats (wave 0), biased var, guarded ----
  if (tid < 64){
    float a0=s_msg[tid]+s_xn[tid], a1=s_msg[tid+64]+s_xn[tid+64];
    float s1=a0+a1, s2=a0*a0+a1*a1;
    #pragma unroll
    for (int off=1;off<64;off<<=1){
      s1 += __shfl_xor(s1,off);
      s2 += __shfl_xor(s2,off);
    }
    if (tid==0){
      float m   = s1*(1.f/Dd);
      float var = fmaxf(s2*(1.f/Dd) - m*m, 0.f);
      s_mv[0]=m;
      s_mv[1]=rsqrtf(var+1e-5f);
    }
  }
  __syncthreads();
  if (tid < Dd){
    float msg = s_msg[tid]+s_xn[tid];
    s_xn[tid] = (msg - s_mv[0])*s_mv[1]*ln_g[tid] + ln_b[tid];
  }
  __syncthreads();

  // ---- delta_s = xn @ out_w + out_b (4 segments of 32 k) ----
  {
    int dp = tid & 127, seg = tid >> 7;
    float pa = 0.f;
    #pragma unroll 8
    for (int k=seg*32;k<seg*32+32;k++)
      pa += s_xn[k]*out_w[k*Dd+dp];
    s_part[seg][dp]=pa;
  }
  __syncthreads();
  if (tid < Dd)
    out_s[(size_t)bi*Dd+tid] = s_part[0][tid]+s_part[1][tid]+s_part[2][tid]+s_part[3][tid]+out_b[tid];
}

extern "C" void kernel_launch(void* const* d_in, const int* in_sizes, int n_in,
                              void* d_out, int out_size, void* d_ws, size_t ws_size,
                              hipStream_t stream) {
  const float* node_s = (const float*)d_in[0];
  const float* node_v = (const float*)d_in[1];
  // d_in[2] = node_t (unused by reference)
  const float* rbf    = (const float*)d_in[3];
  const float* r_hat  = (const float*)d_in[4];
  const float* maskp  = (const float*)d_in[5];
  const float* r0w1=(const float*)d_in[6],  *r0b1=(const float*)d_in[7];
  const float* r0w2=(const float*)d_in[8],  *r0b2=(const float*)d_in[9];
  const float* r1w1=(const float*)d_in[10], *r1b1=(const float*)d_in[11];
  const float* r1w2=(const float*)d_in[12], *r1b2=(const float*)d_in[13];
  const float* r2w1=(const float*)d_in[14], *r2b1=(const float*)d_in[15];
  const float* r2w2=(const float*)d_in[16], *r2b2=(const float*)d_in[17];
  const float* r3w1=(const float*)d_in[18], *r3b1=(const float*)d_in[19];
  const float* r3w2=(const float*)d_in[20], *r3b2=(const float*)d_in[21];
  const float* src_w  =(const float*)d_in[22];
  const float* ln_g   =(const float*)d_in[23];
  const float* ln_b   =(const float*)d_in[24];
  const float* out_w  =(const float*)d_in[25];
  const float* out_b  =(const float*)d_in[26];
  const float* v_scale=(const float*)d_in[27];
  const float* t_scale=(const float*)d_in[28];

  float* hT = (float*)d_ws;                      // h transposed [b][d][j], 256 KiB
  float* out_s = (float*)d_out;
  float* out_v = out_s + (size_t)Bb*Nn*Dd;
  float* out_t = out_v + (size_t)Bb*Nn*3*Dd;

  hproj_kernel<<<dim3(Bb*Nn), dim3(Dd), 0, stream>>>(node_s, src_w, hT);
  se3_mfma6<<<dim3(Bb*Nn), dim3(512), 0, stream>>>(
      node_v, rbf, r_hat, maskp,
      r0w1,r0b1,r0w2,r0b2, r1w1,r1b1,r1w2,r1b2,
      r2w1,r2b1,r2w2,r2b2, r3w1,r3b1,r3w2,r3b2,
      ln_g, ln_b, out_w, out_b, v_scale, t_scale,
      hT, out_s, out_v, out_t);
}

// Round 10
// 225.155 us; speedup vs baseline: 1.1622x; 1.1622x over previous
//
#include <hip/hip_runtime.h>

#define Bb 2
#define Nn 256
#define Dd 128
#define Rr 32

typedef unsigned short u16;
typedef unsigned int   u32;
typedef __attribute__((ext_vector_type(8))) short bf16x8;
typedef __attribute__((ext_vector_type(4))) float f32x4;
typedef __attribute__((ext_vector_type(2))) u32   u32x2;

__device__ __forceinline__ short f2bfs(float f){
  u32 u = __float_as_uint(f);
  u += 0x7FFFu + ((u >> 16) & 1u);   // RNE
  return (short)(u >> 16);
}
__device__ __forceinline__ u16 f2bf(float f){
  u32 u = __float_as_uint(f);
  u += 0x7FFFu + ((u >> 16) & 1u);
  return (u16)(u >> 16);
}

// ---- kernel 1: h_T[b][d][i] = (node_s @ src_w)^T  (fp32) -------------------
__global__ __launch_bounds__(128) void hproj_kernel(
    const float* __restrict__ node_s, const float* __restrict__ src_w,
    float* __restrict__ hT_out){
  __shared__ float s_row[Dd];
  const int bi = blockIdx.x, d = threadIdx.x;
  const int b = bi >> 8, i = bi & 255;
  s_row[d] = node_s[(size_t)bi*Dd + d];
  __syncthreads();
  float acc = 0.f;
  #pragma unroll 8
  for (int k=0;k<Dd;k++) acc += s_row[k]*src_w[k*Dd + d];
  hT_out[((size_t)b*Dd + d)*Nn + i] = acc;   // transposed: [d][j]
}

// ---- kernel 2: all-MFMA pipeline, one block per (b,i), 8 waves -------------
// Waves 0-3: j half [0,128); waves 4-7: j half [128,256).
// Within a half, wave ws owns d-cols [ws*32, ws*32+32).
// rbf fragments register-cached across the p loop (loaded once).
// launch_bounds(512,2): VGPR cap 128 — (512,4) capped at 64 and spilled
// 290 MB of scratch traffic per dispatch (R9 post-mortem).
__global__ __launch_bounds__(512,2) void se3_mfma7(
    const float* __restrict__ node_v,
    const float* __restrict__ rbf,
    const float* __restrict__ r_hat,
    const float* __restrict__ maskp,
    const float* __restrict__ r0w1, const float* __restrict__ r0b1,
    const float* __restrict__ r0w2, const float* __restrict__ r0b2,
    const float* __restrict__ r1w1, const float* __restrict__ r1b1,
    const float* __restrict__ r1w2, const float* __restrict__ r1b2,
    const float* __restrict__ r2w1, const float* __restrict__ r2b1,
    const float* __restrict__ r2w2, const float* __restrict__ r2b2,
    const float* __restrict__ r3w1, const float* __restrict__ r3b1,
    const float* __restrict__ r3w2, const float* __restrict__ r3b2,
    const float* __restrict__ ln_g, const float* __restrict__ ln_b,
    const float* __restrict__ out_w, const float* __restrict__ out_b,
    const float* __restrict__ v_scale, const float* __restrict__ t_scale,
    const float* __restrict__ hT,
    float* __restrict__ out_s, float* __restrict__ out_v, float* __restrict__ out_t)
{
  // LDS total = 69,336 B (2 blocks/CU)
  __shared__ u16   s_hid[2][64*136];   // 34816: hidden per half, [j][hid]
  __shared__ u16   s_G[8*32*40];       // 20480: per-wave G_T[d][j(32)]
  __shared__ u16   s_YT[10*264];       //  5280: 0=mask,1-3=Y1*m,4-8=Y2*m,9=mask
  __shared__ u16   s_Y1r[3*264];       //  1584: raw Y1 (dot MFMA A)
  __shared__ float s_redh[Dd][10];     //  5120: cross-half partials
  __shared__ float s_msg[Dd];          //   512
  __shared__ float s_xn[Dd];           //   512
  __shared__ float s_part[4][Dd];      //  2048
  __shared__ float s_mv[2];            //     8

  const int tid  = threadIdx.x;
  const int bi   = blockIdx.x;            // b*N + i
  const int b    = bi >> 8;
  const int lane = tid & 63;
  const int w    = tid >> 6;              // wave 0..7
  const int half = w >> 2;                // j half
  const int ws   = w & 3;                 // wave-in-set
  const int q    = lane >> 4;             // quad
  const int cc   = lane & 15;
  const int dbase= ws*32;
  const int jbH  = half*128;              // this half's j base

  // ---- setup: stacked-Y rows (mask folded), raw Y1 (one j per thread) ----
  if (tid < Nn){
    int j = tid;
    size_t pidx = (size_t)bi*Nn + j;
    float mk = maskp[pidx];
    float x = r_hat[pidx*3+0];
    float y = r_hat[pidx*3+1];
    float z = r_hat[pidx*3+2];
    const float SQ3=1.7320508075688772f;   // sqrt(3)
    const float C15=3.8729833462074170f;   // sqrt(15)
    const float C5H=1.1180339887498949f;   // 0.5*sqrt(5)
    float y1a=SQ3*x, y1b=SQ3*y, y1c=SQ3*z;
    s_YT[0*264+j]=f2bf(mk);
    s_YT[1*264+j]=f2bf(y1a*mk);
    s_YT[2*264+j]=f2bf(y1b*mk);
    s_YT[3*264+j]=f2bf(y1c*mk);
    s_YT[4*264+j]=f2bf(C15*x*y*mk);
    s_YT[5*264+j]=f2bf(C15*y*z*mk);
    s_YT[6*264+j]=f2bf(C5H*(3.f*z*z-1.f)*mk);
    s_YT[7*264+j]=f2bf(C15*x*z*mk);
    s_YT[8*264+j]=f2bf(0.5f*C15*(x*x-y*y)*mk);
    s_YT[9*264+j]=f2bf(mk);
    s_Y1r[0*264+j]=f2bf(y1a);
    s_Y1r[1*264+j]=f2bf(y1b);
    s_Y1r[2*264+j]=f2bf(y1c);
  }

  const float* rbf_blk = rbf + (size_t)bi*Nn*Rr;

  // ---- rbf fragments for this half, cached in registers (32 VGPR) ----
  bf16x8 rf[8];
  #pragma unroll
  for (int t=0;t<8;t++){
    const float* rp = rbf_blk + (size_t)(jbH + t*16 + cc)*Rr + q*8;
    f32x4 a0 = *(const f32x4*)rp;
    f32x4 a1 = *(const f32x4*)(rp+4);
    rf[t] = (bf16x8){f2bfs(a0[0]),f2bfs(a0[1]),f2bfs(a0[2]),f2bfs(a0[3]),
                     f2bfs(a1[0]),f2bfs(a1[1]),f2bfs(a1[2]),f2bfs(a1[3])};
  }

  // ---- node_v B-fragments for the dot MFMA: B[k=c][n=d], k<3 on quad 0 ----
  bf16x8 vBf[2];
  {
    const float* nv = node_v + (size_t)bi*3*Dd;
    #pragma unroll
    for (int nt=0;nt<2;nt++){
      int dd = dbase+nt*16+cc;
      bf16x8 t = {0,0,0,0,0,0,0,0};
      if (q==0){
        t[0]=f2bfs(nv[0*Dd+dd]);
        t[1]=f2bfs(nv[1*Dd+dd]);
        t[2]=f2bfs(nv[2*Dd+dd]);
      }
      vBf[nt]=t;
    }
  }

  const f32x4 zf = {0.f,0.f,0.f,0.f};
  f32x4 accred[2] = {zf, zf};           // rows 0..9 = the 10 reduced outputs

  #pragma unroll 1
  for (int p=0;p<4;p++){
    const float* W1p = (p==0)?r0w1:(p==1)?r1w1:(p==2)?r2w1:r3w1;
    const float* B1p = (p==0)?r0b1:(p==1)?r1b1:(p==2)?r2b1:r3b1;
    const float* W2p = (p==0)?r0w2:(p==1)?r1w2:(p==2)?r2w2:r3w2;
    const float* B2p = (p==0)?r0b2:(p==1)?r1b2:(p==2)?r2b2:r3b2;
    const int lo = (p==0)?0:(p==1)?1:(p==2)?4:9;
    const int hi = (p==0)?0:(p==1)?3:(p==2)?8:9;
    const u32 gmask = (cc>=lo && cc<=hi) ? 0xFFFFFFFFu : 0u;
    const u16* ytrow = &s_YT[(cc<10?cc:9)*264];

    // per-p fragments: w1f (A of GEMM1) 8 VGPR, w2f (B of GEMM2) 32 VGPR
    bf16x8 w1f[2];
    bf16x8 w2f[2][4];
    f32x4  b1q[2];                     // bias1[hid = dbase+mt*16+q*4+r]
    float  b2v[2];
    #pragma unroll
    for (int mt=0;mt<2;mt++){
      int dd = dbase+mt*16+cc;
      b1q[mt] = *(const f32x4*)(B1p + dbase + mt*16 + q*4);
      b2v[mt] = B2p[dd];
      #pragma unroll
      for (int jj=0;jj<8;jj++)
        w1f[mt][jj] = f2bfs(W1p[(q*8+jj)*Dd + dd]);
      #pragma unroll
      for (int ks=0;ks<4;ks++){
        #pragma unroll
        for (int jj=0;jj<8;jj++)
          w2f[mt][ks][jj] = f2bfs(W2p[(ks*32+q*8+jj)*Dd + dd]);
      }
    }

    #pragma unroll 1
    for (int ch=0; ch<2; ch++){          // 2 chunks of 64 j (this half)
      __syncthreads();                   // s_hid free (all waves' GEMM2 done)
      // ---- GEMM1 (swapped): C1[hid, j] = w1^T @ rbf^T; SiLU; b64 store ----
      #pragma unroll
      for (int jt=0;jt<4;jt++){
        bf16x8 raf = rf[ch*4+jt];
        #pragma unroll
        for (int mt=0;mt<2;mt++){
          f32x4 hc = __builtin_amdgcn_mfma_f32_16x16x32_bf16(w1f[mt], raf, zf, 0,0,0);
          u16 g4[4];
          #pragma unroll
          for (int r=0;r<4;r++){
            float x  = hc[r] + b1q[mt][r];
            float e  = __expf(-x);
            g4[r] = f2bf(x*__builtin_amdgcn_rcpf(1.f+e));
          }
          u32x2 pk = { (u32)g4[0] | ((u32)g4[1]<<16),
                       (u32)g4[2] | ((u32)g4[3]<<16) };
          *(u32x2*)&s_hid[half][(jt*16+cc)*136 + dbase + mt*16 + q*4] = pk;
        }
      }
      __syncthreads();                   // hidden ready
      // ---- GEMM2 + G + per-32j reduction MFMA ----
      #pragma unroll
      for (int pr=0;pr<2;pr++){          // pairs of m-tiles (32 j each)
        #pragma unroll
        for (int ml=0;ml<2;ml++){
          int m = pr*2+ml;
          bf16x8 af[4];
          #pragma unroll
          for (int ks=0;ks<4;ks++)
            af[ks] = *(const bf16x8*)&s_hid[half][(m*16+cc)*136 + ks*32 + q*8];

          f32x4 dotC[2];
          if (p==3){                     // dot(v, Y1) via K=3 MFMA
            bf16x8 aY = {0,0,0,0,0,0,0,0};
            if (q==0){
              int j = jbH + ch*64 + m*16 + cc;
              aY[0]=(short)s_Y1r[0*264+j];
              aY[1]=(short)s_Y1r[1*264+j];
              aY[2]=(short)s_Y1r[2*264+j];
            }
            #pragma unroll
            for (int nt=0;nt<2;nt++)
              dotC[nt] = __builtin_amdgcn_mfma_f32_16x16x32_bf16(aY, vBf[nt], zf, 0,0,0);
          }

          #pragma unroll
          for (int nt=0;nt<2;nt++){
            f32x4 c2 = zf;
            #pragma unroll
            for (int ks=0;ks<4;ks++)
              c2 = __builtin_amdgcn_mfma_f32_16x16x32_bf16(af[ks], w2f[nt][ks], c2, 0,0,0);
            int dd = dbase+nt*16+cc;
            u16 g4[4];
            if (p<3){
              f32x4 h4 = *(const f32x4*)(hT + ((size_t)(b*Dd) + dd)*Nn + jbH + ch*64 + m*16 + q*4);
              #pragma unroll
              for (int r=0;r<4;r++)
                g4[r] = f2bf((c2[r]+b2v[nt]) * h4[r]);
            } else {
              #pragma unroll
              for (int r=0;r<4;r++)
                g4[r] = f2bf((c2[r]+b2v[nt]) * dotC[nt][r]);
            }
            u32x2 pk = { (u32)g4[0] | ((u32)g4[1]<<16),
                         (u32)g4[2] | ((u32)g4[3]<<16) };
            *(u32x2*)&s_G[(w*32 + nt*16 + cc)*40 + ml*16 + q*4] = pk;
          }
        }
        // reduction over this pair's 32 j (intra-wave LDS: in-order, no barrier)
        {
          bf16x8 aR = *(const bf16x8*)(ytrow + jbH + ch*64 + pr*32 + q*8);
          u32* arp = (u32*)&aR;
          arp[0]&=gmask; arp[1]&=gmask; arp[2]&=gmask; arp[3]&=gmask;
          #pragma unroll
          for (int nt=0;nt<2;nt++){
            bf16x8 bG = *(const bf16x8*)&s_G[(w*32 + nt*16 + cc)*40 + q*8];
            accred[nt] = __builtin_amdgcn_mfma_f32_16x16x32_bf16(aR, bG, accred[nt], 0,0,0);
          }
        }
      }
    }
  }

  // ---- cross-half combine + scatter (rows 0..9 only!) ----
  if (half==1){
    #pragma unroll
    for (int nt=0;nt<2;nt++){
      int d = dbase + nt*16 + cc;
      #pragma unroll
      for (int r=0;r<4;r++){
        int rw = q*4 + r;
        if (rw < 10) s_redh[d][rw] = accred[nt][r];   // guard: rows 10..15 are zero/garbage
      }
    }
  }
  __syncthreads();
  if (half==0){
    #pragma unroll
    for (int nt=0;nt<2;nt++){
      int d = dbase + nt*16 + cc;
      #pragma unroll
      for (int r=0;r<4;r++){
        int rw = q*4 + r;
        float val = accred[nt][r] + ((rw<10) ? s_redh[d][rw] : 0.f);
        if (rw==0)      s_msg[d] = val;
        else if (rw<=3) out_v[(size_t)bi*3*Dd + (size_t)(rw-1)*Dd + d] = val*v_scale[d];
        else if (rw<=8) out_t[(size_t)bi*5*Dd + (size_t)(rw-4)*Dd + d] = val*t_scale[d];
        else if (rw==9) s_xn[d] = val;                // guard: rw 10..15 write nothing
      }
    }
  }
  __syncthreads();

  // ---- LayerNorm stats (wave 0), biased var, guarded ----
  if (tid < 64){
    float a0=s_msg[tid]+s_xn[tid], a1=s_msg[tid+64]+s_xn[tid+64];
    float s1=a0+a1, s2=a0*a0+a1*a1;
    #pragma unroll
    for (int off=1;off<64;off<<=1){
      s1 += __shfl_xor(s1,off);
      s2 += __shfl_xor(s2,off);
    }
    if (tid==0){
      float m   = s1*(1.f/Dd);
      float var = fmaxf(s2*(1.f/Dd) - m*m, 0.f);
      s_mv[0]=m;
      s_mv[1]=rsqrtf(var+1e-5f);
    }
  }
  __syncthreads();
  if (tid < Dd){
    float msg = s_msg[tid]+s_xn[tid];
    s_xn[tid] = (msg - s_mv[0])*s_mv[1]*ln_g[tid] + ln_b[tid];
  }
  __syncthreads();

  // ---- delta_s = xn @ out_w + out_b (4 segments of 32 k) ----
  {
    int dp = tid & 127, seg = tid >> 7;
    float pa = 0.f;
    #pragma unroll 8
    for (int k=seg*32;k<seg*32+32;k++)
      pa += s_xn[k]*out_w[k*Dd+dp];
    s_part[seg][dp]=pa;
  }
  __syncthreads();
  if (tid < Dd)
    out_s[(size_t)bi*Dd+tid] = s_part[0][tid]+s_part[1][tid]+s_part[2][tid]+s_part[3][tid]+out_b[tid];
}

extern "C" void kernel_launch(void* const* d_in, const int* in_sizes, int n_in,
                              void* d_out, int out_size, void* d_ws, size_t ws_size,
                              hipStream_t stream) {
  const float* node_s = (const float*)d_in[0];
  const float* node_v = (const float*)d_in[1];
  // d_in[2] = node_t (unused by reference)
  const float* rbf    = (const float*)d_in[3];
  const float* r_hat  = (const float*)d_in[4];
  const float* maskp  = (const float*)d_in[5];
  const float* r0w1=(const float*)d_in[6],  *r0b1=(const float*)d_in[7];
  const float* r0w2=(const float*)d_in[8],  *r0b2=(const float*)d_in[9];
  const float* r1w1=(const float*)d_in[10], *r1b1=(const float*)d_in[11];
  const float* r1w2=(const float*)d_in[12], *r1b2=(const float*)d_in[13];
  const float* r2w1=(const float*)d_in[14], *r2b1=(const float*)d_in[15];
  const float* r2w2=(const float*)d_in[16], *r2b2=(const float*)d_in[17];
  const float* r3w1=(const float*)d_in[18], *r3b1=(const float*)d_in[19];
  const float* r3w2=(const float*)d_in[20], *r3b2=(const float*)d_in[21];
  const float* src_w  =(const float*)d_in[22];
  const float* ln_g   =(const float*)d_in[23];
  const float* ln_b   =(const float*)d_in[24];
  const float* out_w  =(const float*)d_in[25];
  const float* out_b  =(const float*)d_in[26];
  const float* v_scale=(const float*)d_in[27];
  const float* t_scale=(const float*)d_in[28];

  float* hT = (float*)d_ws;                      // h transposed [b][d][j], 256 KiB
  float* out_s = (float*)d_out;
  float* out_v = out_s + (size_t)Bb*Nn*Dd;
  float* out_t = out_v + (size_t)Bb*Nn*3*Dd;

  hproj_kernel<<<dim3(Bb*Nn), dim3(Dd), 0, stream>>>(node_s, src_w, hT);
  se3_mfma7<<<dim3(Bb*Nn), dim3(512), 0, stream>>>(
      node_v, rbf, r_hat, maskp,
      r0w1,r0b1,r0w2,r0b2, r1w1,r1b1,r1w2,r1b2,
      r2w1,r2b1,r2w2,r2b2, r3w1,r3b1,r3w2,r3b2,
      ln_g, ln_b, out_w, out_b, v_scale, t_scale,
      hT, out_s, out_v, out_t);
}

// Round 11
// 205.241 us; speedup vs baseline: 1.2749x; 1.0970x over previous
//
#include <hip/hip_runtime.h>

#define Bb 2
#define Nn 256
#define Dd 128
#define Rr 32

typedef unsigned short u16;
typedef unsigned int   u32;
typedef __attribute__((ext_vector_type(8))) short bf16x8;
typedef __attribute__((ext_vector_type(4))) float f32x4;
typedef __attribute__((ext_vector_type(2))) u32   u32x2;

__device__ __forceinline__ short f2bfs(float f){
  u32 u = __float_as_uint(f);
  u += 0x7FFFu + ((u >> 16) & 1u);   // RNE
  return (short)(u >> 16);
}
__device__ __forceinline__ u16 f2bf(float f){
  u32 u = __float_as_uint(f);
  u += 0x7FFFu + ((u >> 16) & 1u);
  return (u16)(u >> 16);
}

// ---- kernel 1: prologue — rbf->bf16, weights->bf16 fragment order, hT ------
// grid 512 (one per (b,i)), 256 threads.
__global__ __launch_bounds__(256) void prologue_kernel(
    const float* __restrict__ node_s, const float* __restrict__ src_w,
    const float* __restrict__ rbf,
    const float* __restrict__ r0w1, const float* __restrict__ r0w2,
    const float* __restrict__ r1w1, const float* __restrict__ r1w2,
    const float* __restrict__ r2w1, const float* __restrict__ r2w2,
    const float* __restrict__ r3w1, const float* __restrict__ r3w2,
    float* __restrict__ hT, u16* __restrict__ rbf_bf,
    u16* __restrict__ w1T, u16* __restrict__ w2T)
{
  __shared__ float s_row[Dd];
  const int bi = blockIdx.x, tid = threadIdx.x;
  const int b = bi >> 8, i = bi & 255;

  // rbf slice for this bi: 8192 f32 -> bf16 (vectorized, coalesced)
  {
    const f32x4* rsrc = (const f32x4*)(rbf + (size_t)bi*Nn*Rr);
    u32x2* rdst = (u32x2*)(rbf_bf + (size_t)bi*Nn*Rr);
    #pragma unroll 2
    for (int v=tid; v<2048; v+=256){
      f32x4 a = rsrc[v];
      u32x2 pk = { (u32)f2bf(a[0]) | ((u32)f2bf(a[1])<<16),
                   (u32)f2bf(a[2]) | ((u32)f2bf(a[3])<<16) };
      rdst[v] = pk;
    }
  }
  // weights: blocks 0..255 -> w2T (65536 elems), 256..319 -> w1T (16384)
  if (bi < 256){
    int idx = bi*256 + tid;            // = p*16384 + d*128 + k
    int p = idx >> 14, rem = idx & 16383;
    int d = rem >> 7, k = rem & 127;
    const float* w2 = (p==0)?r0w2:(p==1)?r1w2:(p==2)?r2w2:r3w2;
    w2T[idx] = f2bf(w2[k*Dd + d]);
  } else if (bi < 320){
    int idx = (bi-256)*256 + tid;      // = p*4096 + d*32 + r
    int p = idx >> 12, rem = idx & 4095;
    int d = rem >> 5, r = rem & 31;
    const float* w1 = (p==0)?r0w1:(p==1)?r1w1:(p==2)?r2w1:r3w1;
    w1T[idx] = f2bf(w1[r*Dd + d]);
  }
  // hT[b][d][i] = (node_s @ src_w)^T
  if (tid < Dd) s_row[tid] = node_s[(size_t)bi*Dd + tid];
  __syncthreads();
  if (tid < Dd){
    float acc = 0.f;
    #pragma unroll 8
    for (int k=0;k<Dd;k++) acc += s_row[k]*src_w[k*Dd + tid];
    hT[((size_t)b*Dd + tid)*Nn + i] = acc;
  }
}

// ---- kernel 2: main — one block per (b,i,half), 4 waves --------------------
// Wave ws owns d-cols [ws*32, ws*32+32). 128 j per block in 2 chunks of 64.
// All MFMA fragments loaded pre-converted (bf16) from ws. Writes 10x128 fp32
// partials to P[gb]. launch_bounds(256,3): VGPR cap ~170, no spill (R9/R10
// lesson: register-caching rbf or tight caps -> 30-290 MB scratch traffic).
__global__ __launch_bounds__(256,3) void se3_main(
    const float* __restrict__ node_v,
    const u16*  __restrict__ rbf_bf,
    const float* __restrict__ r_hat,
    const float* __restrict__ maskp,
    const float* __restrict__ r0b1, const float* __restrict__ r0b2,
    const float* __restrict__ r1b1, const float* __restrict__ r1b2,
    const float* __restrict__ r2b1, const float* __restrict__ r2b2,
    const float* __restrict__ r3b1, const float* __restrict__ r3b2,
    const u16*  __restrict__ w1T, const u16* __restrict__ w2T,
    const float* __restrict__ hT,
    float* __restrict__ P)
{
  // LDS = 17408 + 10240 + 2720 + 816 = 31,184 B
  __shared__ u16 s_hid[64*136];        // hidden for 64-j chunk, [j][hid]
  __shared__ u16 s_G[4*32*40];         // per-wave G_T[d][j(32)]
  __shared__ u16 s_YT[10*136];         // 0=mask,1-3=Y1*m,4-8=Y2*m,9=mask (this half)
  __shared__ u16 s_Y1r[3*136];         // raw Y1 (dot MFMA A), this half

  const int tid  = threadIdx.x;
  const int gb   = blockIdx.x;            // (b*N+i)*2 + half
  const int bi   = gb >> 1;
  const int b    = bi >> 8;
  const int half = gb & 1;
  const int lane = tid & 63;
  const int w    = tid >> 6;              // wave 0..3
  const int q    = lane >> 4;             // quad
  const int cc   = lane & 15;
  const int dbase= w*32;
  const int jbH  = half*128;              // this half's j base

  // ---- setup: stacked-Y rows (mask folded), raw Y1 for this half ----
  if (tid < 128){
    int jl = tid;                         // local j
    size_t pidx = (size_t)bi*Nn + jbH + jl;
    float mk = maskp[pidx];
    float x = r_hat[pidx*3+0];
    float y = r_hat[pidx*3+1];
    float z = r_hat[pidx*3+2];
    const float SQ3=1.7320508075688772f;   // sqrt(3)
    const float C15=3.8729833462074170f;   // sqrt(15)
    const float C5H=1.1180339887498949f;   // 0.5*sqrt(5)
    float y1a=SQ3*x, y1b=SQ3*y, y1c=SQ3*z;
    s_YT[0*136+jl]=f2bf(mk);
    s_YT[1*136+jl]=f2bf(y1a*mk);
    s_YT[2*136+jl]=f2bf(y1b*mk);
    s_YT[3*136+jl]=f2bf(y1c*mk);
    s_YT[4*136+jl]=f2bf(C15*x*y*mk);
    s_YT[5*136+jl]=f2bf(C15*y*z*mk);
    s_YT[6*136+jl]=f2bf(C5H*(3.f*z*z-1.f)*mk);
    s_YT[7*136+jl]=f2bf(C15*x*z*mk);
    s_YT[8*136+jl]=f2bf(0.5f*C15*(x*x-y*y)*mk);
    s_YT[9*136+jl]=f2bf(mk);
    s_Y1r[0*136+jl]=f2bf(y1a);
    s_Y1r[1*136+jl]=f2bf(y1b);
    s_Y1r[2*136+jl]=f2bf(y1c);
  }

  // ---- node_v B-fragments for the dot MFMA: B[k=c][n=d], k<3 on quad 0 ----
  bf16x8 vBf[2];
  {
    const float* nv = node_v + (size_t)bi*3*Dd;
    #pragma unroll
    for (int nt=0;nt<2;nt++){
      int dd = dbase+nt*16+cc;
      bf16x8 t = {0,0,0,0,0,0,0,0};
      if (q==0){
        t[0]=f2bfs(nv[0*Dd+dd]);
        t[1]=f2bfs(nv[1*Dd+dd]);
        t[2]=f2bfs(nv[2*Dd+dd]);
      }
      vBf[nt]=t;
    }
  }

  const u16* rbf_half = rbf_bf + ((size_t)bi*Nn + jbH)*Rr;

  const f32x4 zf = {0.f,0.f,0.f,0.f};
  f32x4 accred[2] = {zf, zf};           // rows 0..9 = the 10 reduced outputs

  #pragma unroll 1
  for (int p=0;p<4;p++){
    const float* B1p = (p==0)?r0b1:(p==1)?r1b1:(p==2)?r2b1:r3b1;
    const float* B2p = (p==0)?r0b2:(p==1)?r1b2:(p==2)?r2b2:r3b2;
    const u16*   W1p = w1T + p*Dd*Rr;
    const u16*   W2p = w2T + p*Dd*Dd;
    const int lo = (p==0)?0:(p==1)?1:(p==2)?4:9;
    const int hi = (p==0)?0:(p==1)?3:(p==2)?8:9;
    const u32 gmask = (cc>=lo && cc<=hi) ? 0xFFFFFFFFu : 0u;
    const u16* ytrow = &s_YT[(cc<10?cc:9)*136];

    // per-p fragments: all single b128 loads (pre-converted)
    bf16x8 w1f[2];
    bf16x8 w2f[2][4];
    f32x4  b1q[2];                     // bias1[hid = dbase+mt*16+q*4+r]
    float  b2v[2];
    #pragma unroll
    for (int mt=0;mt<2;mt++){
      int dd = dbase+mt*16+cc;
      b1q[mt] = *(const f32x4*)(B1p + dbase + mt*16 + q*4);
      b2v[mt] = B2p[dd];
      w1f[mt] = *(const bf16x8*)(W1p + dd*Rr + q*8);
      #pragma unroll
      for (int ks=0;ks<4;ks++)
        w2f[mt][ks] = *(const bf16x8*)(W2p + dd*Dd + ks*32 + q*8);
    }

    #pragma unroll 1
    for (int ch=0; ch<2; ch++){          // 2 chunks of 64 j (this half)
      __syncthreads();                   // s_hid free (all waves' GEMM2 done)
      // ---- GEMM1 (swapped): C1[hid, j] = w1^T @ rbf^T; SiLU; b64 store ----
      #pragma unroll
      for (int jt=0;jt<4;jt++){
        bf16x8 raf = *(const bf16x8*)(rbf_half + (size_t)(ch*64 + jt*16 + cc)*Rr + q*8);
        #pragma unroll
        for (int mt=0;mt<2;mt++){
          f32x4 hc = __builtin_amdgcn_mfma_f32_16x16x32_bf16(w1f[mt], raf, zf, 0,0,0);
          u16 g4[4];
          #pragma unroll
          for (int r=0;r<4;r++){
            float x  = hc[r] + b1q[mt][r];
            float e  = __expf(-x);
            g4[r] = f2bf(x*__builtin_amdgcn_rcpf(1.f+e));
          }
          u32x2 pk = { (u32)g4[0] | ((u32)g4[1]<<16),
                       (u32)g4[2] | ((u32)g4[3]<<16) };
          *(u32x2*)&s_hid[(jt*16+cc)*136 + dbase + mt*16 + q*4] = pk;
        }
      }
      __syncthreads();                   // hidden ready
      // ---- GEMM2 + G + per-32j reduction MFMA ----
      #pragma unroll
      for (int pr=0;pr<2;pr++){          // pairs of m-tiles (32 j each)
        #pragma unroll
        for (int ml=0;ml<2;ml++){
          int m = pr*2+ml;
          bf16x8 af[4];
          #pragma unroll
          for (int ks=0;ks<4;ks++)
            af[ks] = *(const bf16x8*)&s_hid[(m*16+cc)*136 + ks*32 + q*8];

          f32x4 dotC[2];
          if (p==3){                     // dot(v, Y1) via K=3 MFMA
            bf16x8 aY = {0,0,0,0,0,0,0,0};
            if (q==0){
              int jl = ch*64 + m*16 + cc;
              aY[0]=(short)s_Y1r[0*136+jl];
              aY[1]=(short)s_Y1r[1*136+jl];
              aY[2]=(short)s_Y1r[2*136+jl];
            }
            #pragma unroll
            for (int nt=0;nt<2;nt++)
              dotC[nt] = __builtin_amdgcn_mfma_f32_16x16x32_bf16(aY, vBf[nt], zf, 0,0,0);
          }

          #pragma unroll
          for (int nt=0;nt<2;nt++){
            f32x4 c2 = zf;
            #pragma unroll
            for (int ks=0;ks<4;ks++)
              c2 = __builtin_amdgcn_mfma_f32_16x16x32_bf16(af[ks], w2f[nt][ks], c2, 0,0,0);
            int dd = dbase+nt*16+cc;
            u16 g4[4];
            if (p<3){
              f32x4 h4 = *(const f32x4*)(hT + ((size_t)(b*Dd) + dd)*Nn + jbH + ch*64 + m*16 + q*4);
              #pragma unroll
              for (int r=0;r<4;r++)
                g4[r] = f2bf((c2[r]+b2v[nt]) * h4[r]);
            } else {
              #pragma unroll
              for (int r=0;r<4;r++)
                g4[r] = f2bf((c2[r]+b2v[nt]) * dotC[nt][r]);
            }
            u32x2 pk = { (u32)g4[0] | ((u32)g4[1]<<16),
                         (u32)g4[2] | ((u32)g4[3]<<16) };
            *(u32x2*)&s_G[(w*32 + nt*16 + cc)*40 + ml*16 + q*4] = pk;
          }
        }
        // reduction over this pair's 32 j (intra-wave LDS: in-order, no barrier)
        {
          bf16x8 aR = *(const bf16x8*)(ytrow + ch*64 + pr*32 + q*8);
          u32* arp = (u32*)&aR;
          arp[0]&=gmask; arp[1]&=gmask; arp[2]&=gmask; arp[3]&=gmask;
          #pragma unroll
          for (int nt=0;nt<2;nt++){
            bf16x8 bG = *(const bf16x8*)&s_G[(w*32 + nt*16 + cc)*40 + q*8];
            accred[nt] = __builtin_amdgcn_mfma_f32_16x16x32_bf16(aR, bG, accred[nt], 0,0,0);
          }
        }
      }
    }
  }

  // ---- write 10x128 fp32 partials for this (bi,half) ----
  float* Pp = P + (size_t)gb*1280;
  #pragma unroll
  for (int nt=0;nt<2;nt++){
    int d = dbase + nt*16 + cc;
    #pragma unroll
    for (int r=0;r<4;r++){
      int rw = q*4 + r;
      if (rw < 10) Pp[rw*Dd + d] = accred[nt][r];
    }
  }
}

// ---- kernel 3: finalize — combine halves, scale, LN, out GEMM --------------
// grid 512 (one per (b,i)), 128 threads.
__global__ __launch_bounds__(128) void finalize_kernel(
    const float* __restrict__ P,
    const float* __restrict__ ln_g, const float* __restrict__ ln_b,
    const float* __restrict__ out_w, const float* __restrict__ out_b,
    const float* __restrict__ v_scale, const float* __restrict__ t_scale,
    float* __restrict__ out_s, float* __restrict__ out_v, float* __restrict__ out_t)
{
  __shared__ float s_msg[Dd];
  __shared__ float s_xn[Dd];
  __shared__ float s_mv[2];
  const int bi = blockIdx.x, d = threadIdx.x;
  const float* P0 = P + (size_t)(bi*2+0)*1280;
  const float* P1 = P + (size_t)(bi*2+1)*1280;

  float v[10];
  #pragma unroll
  for (int rw=0;rw<10;rw++) v[rw] = P0[rw*Dd+d] + P1[rw*Dd+d];

  s_msg[d] = v[0] + v[9];
  float vs = v_scale[d], ts = t_scale[d];
  size_t ovb = (size_t)bi*3*Dd + d;
  out_v[ovb + 0*Dd] = v[1]*vs;
  out_v[ovb + 1*Dd] = v[2]*vs;
  out_v[ovb + 2*Dd] = v[3]*vs;
  size_t otb = (size_t)bi*5*Dd + d;
  #pragma unroll
  for (int c=0;c<5;c++) out_t[otb + (size_t)c*Dd] = v[4+c]*ts;
  __syncthreads();

  if (d < 64){
    float a0=s_msg[d], a1=s_msg[d+64];
    float s1=a0+a1, s2=a0*a0+a1*a1;
    #pragma unroll
    for (int off=1;off<64;off<<=1){
      s1 += __shfl_xor(s1,off);
      s2 += __shfl_xor(s2,off);
    }
    if (d==0){
      float m   = s1*(1.f/Dd);
      float var = fmaxf(s2*(1.f/Dd) - m*m, 0.f);
      s_mv[0]=m;
      s_mv[1]=rsqrtf(var+1e-5f);
    }
  }
  __syncthreads();
  s_xn[d] = (s_msg[d]-s_mv[0])*s_mv[1]*ln_g[d] + ln_b[d];
  __syncthreads();

  float pa = 0.f;
  #pragma unroll 8
  for (int k=0;k<Dd;k++)
    pa += s_xn[k]*out_w[k*Dd+d];
  out_s[(size_t)bi*Dd+d] = pa + out_b[d];
}

extern "C" void kernel_launch(void* const* d_in, const int* in_sizes, int n_in,
                              void* d_out, int out_size, void* d_ws, size_t ws_size,
                              hipStream_t stream) {
  const float* node_s = (const float*)d_in[0];
  const float* node_v = (const float*)d_in[1];
  // d_in[2] = node_t (unused by reference)
  const float* rbf    = (const float*)d_in[3];
  const float* r_hat  = (const float*)d_in[4];
  const float* maskp  = (const float*)d_in[5];
  const float* r0w1=(const float*)d_in[6],  *r0b1=(const float*)d_in[7];
  const float* r0w2=(const float*)d_in[8],  *r0b2=(const float*)d_in[9];
  const float* r1w1=(const float*)d_in[10], *r1b1=(const float*)d_in[11];
  const float* r1w2=(const float*)d_in[12], *r1b2=(const float*)d_in[13];
  const float* r2w1=(const float*)d_in[14], *r2b1=(const float*)d_in[15];
  const float* r2w2=(const float*)d_in[16], *r2b2=(const float*)d_in[17];
  const float* r3w1=(const float*)d_in[18], *r3b1=(const float*)d_in[19];
  const float* r3w2=(const float*)d_in[20], *r3b2=(const float*)d_in[21];
  const float* src_w  =(const float*)d_in[22];
  const float* ln_g   =(const float*)d_in[23];
  const float* ln_b   =(const float*)d_in[24];
  const float* out_w  =(const float*)d_in[25];
  const float* out_b  =(const float*)d_in[26];
  const float* v_scale=(const float*)d_in[27];
  const float* t_scale=(const float*)d_in[28];

  // ws layout (16B-aligned chunks):
  char* ws = (char*)d_ws;
  float* hT     = (float*)ws;                         //   256 KiB
  u16*   rbf_bf = (u16*)(ws + 262144);                //  8 MiB
  u16*   w1T    = (u16*)(ws + 262144 + 8388608);      //   32 KiB
  u16*   w2T    = (u16*)(ws + 262144 + 8388608 + 32768);          // 128 KiB
  float* P      = (float*)(ws + 262144 + 8388608 + 32768 + 131072);// 5 MiB

  float* out_s = (float*)d_out;
  float* out_v = out_s + (size_t)Bb*Nn*Dd;
  float* out_t = out_v + (size_t)Bb*Nn*3*Dd;

  prologue_kernel<<<dim3(Bb*Nn), dim3(256), 0, stream>>>(
      node_s, src_w, rbf,
      r0w1, r0w2, r1w1, r1w2, r2w1, r2w2, r3w1, r3w2,
      hT, rbf_bf, w1T, w2T);
  se3_main<<<dim3(Bb*Nn*2), dim3(256), 0, stream>>>(
      node_v, rbf_bf, r_hat, maskp,
      r0b1, r0b2, r1b1, r1b2, r2b1, r2b2, r3b1, r3b2,
      w1T, w2T, hT, P);
  finalize_kernel<<<dim3(Bb*Nn), dim3(128), 0, stream>>>(
      P, ln_g, ln_b, out_w, out_b, v_scale, t_scale,
      out_s, out_v, out_t);
}